// Round 8
// baseline (3462.948 us; speedup 1.0000x reference)
//
#include <hip/hip_runtime.h>
#include <stdint.h>

#define NB 2048
#define OBSD 256
#define POP 10
#define NIN 2560       // OBS_DIM * POP_DIM
#define H 256          // HID1 == HID2
#define OUTP 80        // ACT_DIM * DE_POP
#define TS 25

// correctly-rounded fp32 exp (fp64 exp then round) — best estimator of SVML
// high-accuracy expf (~0.5 ulp) that numpy dispatches to on AVX512 hosts.
__device__ __forceinline__ float exp_cr(float x) {
    return (float)exp((double)x);
}

// ---------------- K0: transpose weights into fp32 [k][n] layouts in ws ----------------
__global__ __launch_bounds__(256) void k0_transpose(
    const float* __restrict__ w1, const float* __restrict__ w2, const float* __restrict__ w3,
    float* __restrict__ w1t, float* __restrict__ w2t, float* __restrict__ w3t)
{
    int idx = blockIdx.x * 256 + threadIdx.x;
    const int N1 = NIN * H;       // 655360
    const int N2 = H * H;         // 65536
    const int N3 = H * OUTP;      // 20480
    if (idx < N1) {
        int i = idx >> 8, j = idx & 255;
        w1t[idx] = w1[j * NIN + i];
    } else if (idx < N1 + N2) {
        int k = idx - N1;
        int i = k >> 8, j = k & 255;
        w2t[k] = w2[j * H + i];
    } else if (idx < N1 + N2 + N3) {
        int k = idx - N1 - N2;
        int i = k / OUTP, j = k - i * OUTP;
        w3t[k] = w3[j * H + i];
    }
}

// One LIF step, numpy-faithful per-op rounding (no contraction):
// c' = ((c*0.5) + x) + b ; v = ((vp*0.75)*(1-s)) + c' ;
// vth = 0.25 + 0.5*(exp((vp-v)/3) - 1) ; s' = (v > vth)
__device__ __forceinline__ void lif_step(float x, float bv, float& c, float& v, float& s) {
    float cn = __fadd_rn(__fadd_rn(__fmul_rn(c, 0.5f), x), bv);
    c = cn;
    float vp = v;
    float t  = __fmul_rn(__fmul_rn(vp, 0.75f), __fadd_rn(1.0f, -s));
    float vn = __fadd_rn(t, cn);
    float ag = __fdiv_rn(__fadd_rn(vp, -vn), 3.0f);
    float ex = exp_cr(ag);
    float vth = __fadd_rn(0.25f, __fmul_rn(0.5f, __fadd_rn(ex, -1.0f)));
    v = vn;
    s = (vn > vth) ? 1.0f : 0.0f;
}

// ---------------- K1: fused encoder + event GEMM1 + LIF scan + decode ----------------
// Block = 256 threads = 4 waves; wave w owns batch row b0+w for the encoder,
// event-GEMM1 and GEMM3; layers 1&2 LIF + GEMM2 use thread-owns-neuron layout.
__global__ __launch_bounds__(256) void k1_fused(
    const float* __restrict__ obs, const float* __restrict__ emean, const float* __restrict__ estd,
    const float* __restrict__ w1t, const float* __restrict__ w2t, const float* __restrict__ w3t,
    const float* __restrict__ b1, const float* __restrict__ b2, const float* __restrict__ b3,
    const float* __restrict__ dw, const float* __restrict__ db, float* __restrict__ out)
{
    // maskL [4][2560] uint (40960 B) dead after Phase B; curF [5][4][256] float
    // (20480 B) aliases it during the scan.
    __shared__ __align__(16) char unionbuf[4 * NIN * 4];
    uint32_t (*maskL)[NIN] = (uint32_t (*)[NIN])unionbuf;
    float (*curF)[4][H]    = (float (*)[4][H])unionbuf;

    __shared__ float4 s1q[H];        // s1 spikes, [i] -> (r0..r3)
    __shared__ float  s2qT[4][H];    // s2 spikes, [r][i]
    __shared__ float  cnt3[4][OUTP]; // layer-3 spike counts

    const int tid = threadIdx.x;
    const int wave = tid >> 6, lane = tid & 63;
    const int b0 = blockIdx.x * 4;
    const int b = b0 + wave;

    // ---- Phase A: population encoding, numpy-faithful fp32 op-by-op ----
    for (int k = 0; k < NIN / 64; ++k) {
        int i = k * 64 + lane;
        uint32_t o = (uint32_t)i / 10u;
        float x  = obs[b * OBSD + o];
        float mu = emean[i];
        float sd = estd[i];
        float d  = __fadd_rn(x, -mu);
        float d2 = __fmul_rn(d, d);
        float nm = __fmul_rn(-0.5f, d2);          // exact (pow2 scale)
        float dn = __fmul_rn(sd, sd);
        float a  = exp_cr(__fdiv_rn(nm, dn));
        float volt = 0.0f;
        uint32_t m = 0;
        #pragma unroll
        for (int t = 0; t < TS; ++t) {
            volt = __fadd_rn(volt, a);
            if (volt > 0.999f) { m |= (1u << t); volt = __fadd_rn(volt, -0.999f); }
        }
        maskL[wave][i] = m;
    }
    __syncthreads();

    // ---- Phase B: event-driven GEMM1 with OpenBLAS K-blocking (SkylakeX Q=320) ----
    // OpenBLAS on AVX512 hosts (Zen4+ -> SkylakeX/Cooperlake kernels): Kc=320,
    // K=2560 -> 8 blocks of 320. Per C element: left-assoc sum of per-block
    // ascending-k FMA chains (zeros contribute exactly nothing -> event chain
    // within a block matches bitwise). Walk the mask list once per 5-t chunk.
    float acc[TS][4];
    #pragma unroll
    for (int t = 0; t < TS; ++t) { acc[t][0]=0.f; acc[t][1]=0.f; acc[t][2]=0.f; acc[t][3]=0.f; }

    const uint4* mq = (const uint4*)&maskL[wave][0];

    #pragma unroll
    for (int c5 = 0; c5 < 5; ++c5) {
        const int sh = 5 * c5;
        #pragma unroll
        for (int blk = 0; blk < 8; ++blk) {
            float part[5][4];
            #pragma unroll
            for (int tt = 0; tt < 5; ++tt) { part[tt][0]=0.f; part[tt][1]=0.f; part[tt][2]=0.f; part[tt][3]=0.f; }

            for (int c = blk * 80; c < (blk + 1) * 80; ++c) {   // 320 inputs = 80 uint4
                uint4 mm = mq[c];   // broadcast read (same addr across the wave)
                #pragma unroll
                for (int u = 0; u < 4; ++u) {
                    uint32_t m = (uint32_t)__builtin_amdgcn_readfirstlane(
                                     (int)(((&mm.x)[u] >> sh) & 31u));
                    if (m) {
                        int i = c * 4 + u;
                        const float4 w = *(const float4*)(w1t + (size_t)i * H + lane * 4);
                        #pragma unroll
                        for (int tt = 0; tt < 5; ++tt) {
                            if (m & (1u << tt)) {
                                part[tt][0] = __fadd_rn(part[tt][0], w.x);
                                part[tt][1] = __fadd_rn(part[tt][1], w.y);
                                part[tt][2] = __fadd_rn(part[tt][2], w.z);
                                part[tt][3] = __fadd_rn(part[tt][3], w.w);
                            }
                        }
                    }
                }
            }
            #pragma unroll
            for (int tt = 0; tt < 5; ++tt) {
                acc[sh + tt][0] = __fadd_rn(acc[sh + tt][0], part[tt][0]);
                acc[sh + tt][1] = __fadd_rn(acc[sh + tt][1], part[tt][1]);
                acc[sh + tt][2] = __fadd_rn(acc[sh + tt][2], part[tt][2]);
                acc[sh + tt][3] = __fadd_rn(acc[sh + tt][3], part[tt][3]);
            }
        }
    }
    __syncthreads();   // maskL reads done before curF writes (aliased memory)

    // ---- Phase C: 25-step LIF scan in 5-step chunks ----
    const float b1v = b1[tid];
    const float b2v = b2[tid];
    const int j3a = lane;
    const int j3b = 64 + (lane & 15);
    const float b3a = b3[j3a];
    const float b3b = b3[j3b];

    float c1[4]={0,0,0,0}, v1[4]={0,0,0,0}, s1s[4]={0,0,0,0};
    float c2[4]={0,0,0,0}, v2[4]={0,0,0,0}, s2s[4]={0,0,0,0};
    float c3a=0, v3a=0, s3a=0, cta=0;
    float c3b=0, v3b=0, s3b=0, ctb=0;

    #pragma unroll
    for (int c5 = 0; c5 < 5; ++c5) {
        #pragma unroll
        for (int tt = 0; tt < 5; ++tt) {
            int t = c5 * 5 + tt;
            *(float4*)&curF[tt][wave][lane * 4] =
                make_float4(acc[t][0], acc[t][1], acc[t][2], acc[t][3]);
        }
        __syncthreads();

        for (int tt = 0; tt < 5; ++tt) {
            // ---- layer 1 LIF ----
            float sq[4];
            #pragma unroll
            for (int r = 0; r < 4; ++r) {
                lif_step(curF[tt][r][tid], b1v, c1[r], v1[r], s1s[r]);
                sq[r] = s1s[r];
            }
            s1q[tid] = make_float4(sq[0], sq[1], sq[2], sq[3]);
            __syncthreads();

            // ---- GEMM2: single K-block (K=256<=Q), ascending-i FMA chain ----
            float a0 = 0, a1 = 0, a2 = 0, a3 = 0;
            #pragma unroll 4
            for (int i = 0; i < H; ++i) {
                float w = w2t[i * H + tid];
                float4 s = s1q[i];
                a0 = fmaf(w, s.x, a0);
                a1 = fmaf(w, s.y, a1);
                a2 = fmaf(w, s.z, a2);
                a3 = fmaf(w, s.w, a3);
            }
            float av[4] = {a0, a1, a2, a3};

            // ---- layer 2 LIF ----
            #pragma unroll
            for (int r = 0; r < 4; ++r) {
                lif_step(av[r], b2v, c2[r], v2[r], s2s[r]);
                s2qT[r][tid] = s2s[r];
            }
            __syncthreads();

            // ---- GEMM3 (wave w -> row w), ascending-i FMA chain ----
            float xa = 0, xb = 0;
            #pragma unroll 4
            for (int i = 0; i < H; ++i) {
                float sv = s2qT[wave][i];
                xa = fmaf(sv, w3t[i * OUTP + j3a], xa);
                xb = fmaf(sv, w3t[i * OUTP + j3b], xb);
            }
            // ---- layer 3 LIF ----
            lif_step(xa, b3a, c3a, v3a, s3a);  cta += s3a;
            lif_step(xb, b3b, c3b, v3b, s3b);  ctb += s3b;
            __syncthreads();   // protect s1q/s2qT (and end-of-chunk curF) reuse
        }
    }

    cnt3[wave][j3a] = cta;
    if (lane < 16) cnt3[wave][j3b] = ctb;
    __syncthreads();

    // ---- decode: per-op rounding like np einsum (no FMA) ----
    if (tid < 32) {
        int r = tid >> 3, a = tid & 7;
        float raw = 0.0f;
        #pragma unroll
        for (int p = 0; p < POP; ++p) {
            float po = __fdiv_rn(cnt3[r][a * POP + p], 25.0f);
            raw = __fadd_rn(raw, __fmul_rn(po, dw[a * POP + p]));
        }
        raw = __fadd_rn(raw, db[a]);
        out[(b0 + r) * 8 + a] = (float)tanh((double)raw);
    }
}

extern "C" void kernel_launch(void* const* d_in, const int* in_sizes, int n_in,
                              void* d_out, int out_size, void* d_ws, size_t ws_size,
                              hipStream_t stream) {
    const float* obs   = (const float*)d_in[0];
    const float* emean = (const float*)d_in[1];
    const float* estd  = (const float*)d_in[2];
    const float* w1    = (const float*)d_in[3];
    const float* b1    = (const float*)d_in[4];
    const float* w2    = (const float*)d_in[5];
    const float* b2    = (const float*)d_in[6];
    const float* w3    = (const float*)d_in[7];
    const float* b3    = (const float*)d_in[8];
    const float* dw    = (const float*)d_in[9];
    const float* db    = (const float*)d_in[10];
    float* out = (float*)d_out;

    char* ws = (char*)d_ws;
    float* w1t = (float*)(ws);                 // 655360 * 4 = 2,621,440 B
    float* w2t = (float*)(ws + 2621440);       //  65536 * 4 =   262,144 B
    float* w3t = (float*)(ws + 2883584);       //  20480 * 4 =    81,920 B

    k0_transpose<<<2896, 256, 0, stream>>>(w1, w2, w3, w1t, w2t, w3t);
    k1_fused<<<512, 256, 0, stream>>>(obs, emean, estd, w1t, w2t, w3t,
                                      b1, b2, b3, dw, db, out);
}

// Round 9
// 1436.779 us; speedup vs baseline: 2.4102x; 2.4102x over previous
//
#include <hip/hip_runtime.h>
#include <stdint.h>

#define NB 2048
#define OBSD 256
#define POP 10
#define NIN 2560       // OBS_DIM * POP_DIM
#define H 256          // HID1 == HID2
#define OUTP 80        // ACT_DIM * DE_POP
#define TS 25

// correctly-rounded fp32 exp (fp64 exp then round) — matches SVML high-accuracy
// expf that numpy dispatches to on AVX512 hosts (validated r8: absmax 4.8e-7).
__device__ __forceinline__ float exp_cr(float x) {
    return (float)exp((double)x);
}

__device__ __forceinline__ unsigned long long rfl64(unsigned long long m) {
    // force wave-uniform 64-bit value into SGPRs (scalar while-loops below)
    uint32_t lo = (uint32_t)__builtin_amdgcn_readfirstlane((int)(uint32_t)m);
    uint32_t hi = (uint32_t)__builtin_amdgcn_readfirstlane((int)(uint32_t)(m >> 32));
    return ((unsigned long long)hi << 32) | lo;
}

// ---------------- K0: transpose weights into fp32 [k][n] layouts in ws ----------------
__global__ __launch_bounds__(256) void k0_transpose(
    const float* __restrict__ w1, const float* __restrict__ w2, const float* __restrict__ w3,
    float* __restrict__ w1t, float* __restrict__ w2t, float* __restrict__ w3t)
{
    int idx = blockIdx.x * 256 + threadIdx.x;
    const int N1 = NIN * H;       // 655360
    const int N2 = H * H;         // 65536
    const int N3 = H * OUTP;      // 20480
    if (idx < N1) {
        int i = idx >> 8, j = idx & 255;
        w1t[idx] = w1[j * NIN + i];
    } else if (idx < N1 + N2) {
        int k = idx - N1;
        int i = k >> 8, j = k & 255;
        w2t[k] = w2[j * H + i];
    } else if (idx < N1 + N2 + N3) {
        int k = idx - N1 - N2;
        int i = k / OUTP, j = k - i * OUTP;
        w3t[k] = w3[j * H + i];
    }
}

// One LIF step, numpy-faithful per-op rounding (no contraction):
// c' = ((c*0.5) + x) + b ; v = ((vp*0.75)*(1-s)) + c' ;
// vth = 0.25 + 0.5*(exp((vp-v)/3) - 1) ; s' = (v > vth)
__device__ __forceinline__ void lif_step(float x, float bv, float& c, float& v, float& s) {
    float cn = __fadd_rn(__fadd_rn(__fmul_rn(c, 0.5f), x), bv);
    c = cn;
    float vp = v;
    float t  = __fmul_rn(__fmul_rn(vp, 0.75f), __fadd_rn(1.0f, -s));
    float vn = __fadd_rn(t, cn);
    float ag = __fdiv_rn(__fadd_rn(vp, -vn), 3.0f);
    float ex = exp_cr(ag);
    float vth = __fadd_rn(0.25f, __fmul_rn(0.5f, __fadd_rn(ex, -1.0f)));
    v = vn;
    s = (vn > vth) ? 1.0f : 0.0f;
}

// ---------------- K1: fused, ONE batch row per block (2048 blocks) ----------------
// Thread tid owns hidden neuron tid end-to-end (layers 1&2); threads 0..79 own
// layer-3 neurons. GEMM2/3 are event-driven over ballot bitmasks (bitwise ==
// dense chain: skipped terms are exact fma(w,0,acc) no-ops; fma(w,1,acc) ==
// __fadd_rn). GEMM1 keeps OpenBLAS SkylakeX K-blocking (8 x Kc=320).
__global__ __launch_bounds__(256) void k1_fused(
    const float* __restrict__ obs, const float* __restrict__ emean, const float* __restrict__ estd,
    const float* __restrict__ w1t, const float* __restrict__ w2t, const float* __restrict__ w3t,
    const float* __restrict__ b1, const float* __restrict__ b2, const float* __restrict__ b3,
    const float* __restrict__ dw, const float* __restrict__ db, float* __restrict__ out)
{
    // maskL (uint[2560], 10240 B) is dead after the Phase-B walk; accL
    // (float[25][256], 25600 B) aliases it afterwards (barrier between).
    __shared__ __align__(16) char ub[TS * H * 4];
    uint32_t* maskL = (uint32_t*)ub;
    float*    accL  = (float*)ub;          // accL[t*H + tid]
    __shared__ unsigned long long s1w[2][4], s2w[2][4];   // double-buffered spike masks
    __shared__ float cnt3[OUTP];

    const int tid = threadIdx.x;
    const int wave = tid >> 6, lane = tid & 63;
    const int b = blockIdx.x;

    // ---- Phase A: population encoding, numpy-faithful fp32 op-by-op ----
    for (int k = 0; k < 10; ++k) {
        int i = k * 256 + tid;
        int o = i / 10;
        float x  = obs[b * OBSD + o];
        float mu = emean[i];
        float sd = estd[i];
        float d  = __fadd_rn(x, -mu);
        float d2 = __fmul_rn(d, d);
        float nm = __fmul_rn(-0.5f, d2);
        float dn = __fmul_rn(sd, sd);
        float a  = exp_cr(__fdiv_rn(nm, dn));
        float volt = 0.0f;
        uint32_t m = 0;
        #pragma unroll
        for (int t = 0; t < TS; ++t) {
            volt = __fadd_rn(volt, a);
            if (volt > 0.999f) { m |= (1u << t); volt = __fadd_rn(volt, -0.999f); }
        }
        maskL[i] = m;
    }
    __syncthreads();

    // ---- Phase B: event GEMM1, single walk, K-blocks {320 x 8} left-assoc ----
    float acc[TS];
    #pragma unroll
    for (int t = 0; t < TS; ++t) acc[t] = 0.0f;

    const uint4* mq = (const uint4*)maskL;
    for (int blk = 0; blk < 8; ++blk) {
        float part[TS];
        #pragma unroll
        for (int t = 0; t < TS; ++t) part[t] = 0.0f;

        for (int c = blk * 80; c < blk * 80 + 80; ++c) {   // 320 inputs = 80 uint4
            uint4 mm = mq[c];   // block-uniform broadcast read
            #pragma unroll
            for (int u = 0; u < 4; ++u) {
                uint32_t m = (uint32_t)__builtin_amdgcn_readfirstlane((int)((&mm.x)[u]));
                if (m) {
                    int i = c * 4 + u;
                    float w = w1t[(size_t)i * H + tid];   // coalesced
                    #pragma unroll
                    for (int t = 0; t < TS; ++t)
                        part[t] = __fadd_rn(part[t], (m & (1u << t)) ? w : 0.0f);
                }
            }
        }
        #pragma unroll
        for (int t = 0; t < TS; ++t) acc[t] = __fadd_rn(acc[t], part[t]);
    }
    __syncthreads();   // all maskL reads done before accL writes (aliased)

    #pragma unroll
    for (int t = 0; t < TS; ++t) accL[t * H + tid] = acc[t];
    // (each thread re-reads only its own accL slots — no barrier needed)

    // ---- Phase C: 25-step LIF scan, event-driven GEMM2/GEMM3 ----
    const float b1v = b1[tid];
    const float b2v = b2[tid];
    const float b3v = (tid < OUTP) ? b3[tid] : 0.0f;

    float c1 = 0, v1 = 0, s1 = 0;
    float c2 = 0, v2 = 0, s2 = 0;
    float c3 = 0, v3 = 0, s3 = 0, ct = 0;

    for (int t = 0; t < TS; ++t) {
        const int p = t & 1;
        // ---- layer 1 LIF ----
        lif_step(accL[t * H + tid], b1v, c1, v1, s1);
        unsigned long long bal = __ballot(s1 != 0.0f);
        if (lane == 0) s1w[p][wave] = bal;
        __syncthreads();

        // ---- GEMM2: event-driven ascending-i chain (K=256, single block) ----
        float a0 = 0.0f;
        #pragma unroll
        for (int w = 0; w < 4; ++w) {
            unsigned long long m = rfl64(s1w[p][w]);
            while (m) {
                int i = (w << 6) + __builtin_ctzll(m);
                m &= m - 1;
                a0 = __fadd_rn(a0, w2t[i * H + tid]);
            }
        }
        // ---- layer 2 LIF ----
        lif_step(a0, b2v, c2, v2, s2);
        bal = __ballot(s2 != 0.0f);
        if (lane == 0) s2w[p][wave] = bal;
        __syncthreads();

        // ---- GEMM3 + layer 3 LIF (threads 0..79) ----
        if (tid < OUTP) {
            float x = 0.0f;
            #pragma unroll
            for (int w = 0; w < 4; ++w) {
                unsigned long long m = rfl64(s2w[p][w]);
                while (m) {
                    int i = (w << 6) + __builtin_ctzll(m);
                    m &= m - 1;
                    x = __fadd_rn(x, w3t[i * OUTP + tid]);
                }
            }
            lif_step(x, b3v, c3, v3, s3);
            ct += s3;
        }
        // no barrier here: s1w/s2w are double-buffered (slot reused at t+2,
        // separated by the two barriers of step t+1)
    }

    if (tid < OUTP) cnt3[tid] = ct;
    __syncthreads();

    // ---- decode: per-op rounding like np einsum (no FMA) ----
    if (tid < 8) {
        float raw = 0.0f;
        #pragma unroll
        for (int pp = 0; pp < POP; ++pp) {
            float po = __fdiv_rn(cnt3[tid * POP + pp], 25.0f);
            raw = __fadd_rn(raw, __fmul_rn(po, dw[tid * POP + pp]));
        }
        raw = __fadd_rn(raw, db[tid]);
        out[b * 8 + tid] = (float)tanh((double)raw);
    }
}

extern "C" void kernel_launch(void* const* d_in, const int* in_sizes, int n_in,
                              void* d_out, int out_size, void* d_ws, size_t ws_size,
                              hipStream_t stream) {
    const float* obs   = (const float*)d_in[0];
    const float* emean = (const float*)d_in[1];
    const float* estd  = (const float*)d_in[2];
    const float* w1    = (const float*)d_in[3];
    const float* b1    = (const float*)d_in[4];
    const float* w2    = (const float*)d_in[5];
    const float* b2    = (const float*)d_in[6];
    const float* w3    = (const float*)d_in[7];
    const float* b3    = (const float*)d_in[8];
    const float* dw    = (const float*)d_in[9];
    const float* db    = (const float*)d_in[10];
    float* out = (float*)d_out;

    char* ws = (char*)d_ws;
    float* w1t = (float*)(ws);                 // 655360 * 4 = 2,621,440 B
    float* w2t = (float*)(ws + 2621440);       //  65536 * 4 =   262,144 B
    float* w3t = (float*)(ws + 2883584);       //  20480 * 4 =    81,920 B

    k0_transpose<<<2896, 256, 0, stream>>>(w1, w2, w3, w1t, w2t, w3t);
    k1_fused<<<NB, 256, 0, stream>>>(obs, emean, estd, w1t, w2t, w3t,
                                     b1, b2, b3, dw, db, out);
}

// Round 10
// 871.296 us; speedup vs baseline: 3.9745x; 1.6490x over previous
//
#include <hip/hip_runtime.h>
#include <stdint.h>

#define NB 2048
#define OBSD 256
#define POP 10
#define NIN 2560       // OBS_DIM * POP_DIM
#define H 256          // HID1 == HID2
#define OUTP 80        // ACT_DIM * DE_POP
#define TS 25

// correctly-rounded fp32 exp (fp64 exp then round) — matches SVML high-accuracy
// expf that numpy dispatches to on AVX512 hosts (validated r8: absmax 4.8e-7).
__device__ __forceinline__ float exp_cr(float x) {
    return (float)exp((double)x);
}

// ---------------- K0: transpose weights into fp32 [k][n] layouts in ws ----------------
__global__ __launch_bounds__(256) void k0_transpose(
    const float* __restrict__ w1, const float* __restrict__ w2, const float* __restrict__ w3,
    float* __restrict__ w1t, float* __restrict__ w2t, float* __restrict__ w3t)
{
    int idx = blockIdx.x * 256 + threadIdx.x;
    const int N1 = NIN * H;       // 655360
    const int N2 = H * H;         // 65536
    const int N3 = H * OUTP;      // 20480
    if (idx < N1) {
        int i = idx >> 8, j = idx & 255;
        w1t[idx] = w1[j * NIN + i];
    } else if (idx < N1 + N2) {
        int k = idx - N1;
        int i = k >> 8, j = k & 255;
        w2t[k] = w2[j * H + i];
    } else if (idx < N1 + N2 + N3) {
        int k = idx - N1 - N2;
        int i = k / OUTP, j = k - i * OUTP;
        w3t[k] = w3[j * H + i];
    }
}

// One LIF step, numpy-faithful per-op rounding (no contraction):
// c' = ((c*0.5) + x) + b ; v = ((vp*0.75)*(1-s)) + c' ;
// vth = 0.25 + 0.5*(exp((vp-v)/3) - 1) ; s' = (v > vth)
__device__ __forceinline__ void lif_step(float x, float bv, float& c, float& v, float& s) {
    float cn = __fadd_rn(__fadd_rn(__fmul_rn(c, 0.5f), x), bv);
    c = cn;
    float vp = v;
    float t  = __fmul_rn(__fmul_rn(vp, 0.75f), __fadd_rn(1.0f, -s));
    float vn = __fadd_rn(t, cn);
    float ag = __fdiv_rn(__fadd_rn(vp, -vn), 3.0f);
    float ex = exp_cr(ag);
    float vth = __fadd_rn(0.25f, __fmul_rn(0.5f, __fadd_rn(ex, -1.0f)));
    v = vn;
    s = (vn > vth) ? 1.0f : 0.0f;
}

// Walk a sorted pre-multiplied index list with 8-deep load MLP; the add chain
// stays strictly k-ascending (bitwise == the dense/ctz chain).
__device__ __forceinline__ float walk_list(const float* __restrict__ wmat,
                                           const int* __restrict__ list,
                                           int cnt, int tid) {
    float a = 0.0f;
    int k = 0;
    for (; k + 8 <= cnt; k += 8) {
        uint4 ia = *(const uint4*)&list[k];
        uint4 ib = *(const uint4*)&list[k + 4];
        float w0 = wmat[(int)ia.x + tid];
        float w1 = wmat[(int)ia.y + tid];
        float w2 = wmat[(int)ia.z + tid];
        float w3 = wmat[(int)ia.w + tid];
        float w4 = wmat[(int)ib.x + tid];
        float w5 = wmat[(int)ib.y + tid];
        float w6 = wmat[(int)ib.z + tid];
        float w7 = wmat[(int)ib.w + tid];
        a = __fadd_rn(a, w0); a = __fadd_rn(a, w1);
        a = __fadd_rn(a, w2); a = __fadd_rn(a, w3);
        a = __fadd_rn(a, w4); a = __fadd_rn(a, w5);
        a = __fadd_rn(a, w6); a = __fadd_rn(a, w7);
    }
    for (; k < cnt; ++k) a = __fadd_rn(a, wmat[list[k] + tid]);
    return a;
}

// ---------------- K1: fused, ONE batch row per block (2048 blocks) ----------------
// Thread tid owns hidden neuron tid end-to-end (layers 1&2); threads 0..79 own
// layer-3 neurons. GEMM2/3 walk ballot-built sorted spike lists (bitwise ==
// dense ascending-i chain). GEMM1 keeps OpenBLAS SkylakeX K-blocking (8 x 320).
__global__ __launch_bounds__(256) void k1_fused(
    const float* __restrict__ obs, const float* __restrict__ emean, const float* __restrict__ estd,
    const float* __restrict__ w1t, const float* __restrict__ w2t, const float* __restrict__ w3t,
    const float* __restrict__ b1, const float* __restrict__ b2, const float* __restrict__ b3,
    const float* __restrict__ dw, const float* __restrict__ db, float* __restrict__ out)
{
    // maskL (uint[2560], 10240 B) is dead after the Phase-B walk; accL
    // (float[25][256], 25600 B) aliases it afterwards (barrier between).
    __shared__ __align__(16) char ub[TS * H * 4];
    uint32_t* maskL = (uint32_t*)ub;
    float*    accL  = (float*)ub;          // accL[t*H + tid]
    __shared__ __align__(16) int list1[H];   // spiking layer-1 neurons, i*H
    __shared__ __align__(16) int list2[H];   // spiking layer-2 neurons, i*OUTP
    __shared__ uint32_t cw1[4], cw2[4];
    __shared__ float cnt3[OUTP];

    const int tid = threadIdx.x;
    const int wave = tid >> 6, lane = tid & 63;
    const int b = blockIdx.x;
    const unsigned long long below = (1ull << lane) - 1ull;

    // ---- Phase A: population encoding, numpy-faithful fp32 op-by-op ----
    for (int k = 0; k < 10; ++k) {
        int i = k * 256 + tid;
        int o = i / 10;
        float x  = obs[b * OBSD + o];
        float mu = emean[i];
        float sd = estd[i];
        float d  = __fadd_rn(x, -mu);
        float d2 = __fmul_rn(d, d);
        float nm = __fmul_rn(-0.5f, d2);
        float dn = __fmul_rn(sd, sd);
        float a  = exp_cr(__fdiv_rn(nm, dn));
        float volt = 0.0f;
        uint32_t m = 0;
        #pragma unroll
        for (int t = 0; t < TS; ++t) {
            volt = __fadd_rn(volt, a);
            if (volt > 0.999f) { m |= (1u << t); volt = __fadd_rn(volt, -0.999f); }
        }
        maskL[i] = m;
    }
    __syncthreads();

    // ---- Phase B: event GEMM1, single walk, K-blocks {320 x 8} left-assoc ----
    float acc[TS];
    #pragma unroll
    for (int t = 0; t < TS; ++t) acc[t] = 0.0f;

    const uint4* mq = (const uint4*)maskL;
    for (int blk = 0; blk < 8; ++blk) {
        float part[TS];
        #pragma unroll
        for (int t = 0; t < TS; ++t) part[t] = 0.0f;

        for (int c = blk * 80; c < blk * 80 + 80; ++c) {   // 320 inputs = 80 uint4
            uint4 mm = mq[c];   // block-uniform broadcast read
            #pragma unroll
            for (int u = 0; u < 4; ++u) {
                uint32_t m = (uint32_t)__builtin_amdgcn_readfirstlane((int)((&mm.x)[u]));
                if (m) {
                    int i = c * 4 + u;
                    float w = w1t[(size_t)i * H + tid];   // coalesced
                    #pragma unroll
                    for (int t = 0; t < TS; ++t)
                        part[t] = __fadd_rn(part[t], (m & (1u << t)) ? w : 0.0f);
                }
            }
        }
        #pragma unroll
        for (int t = 0; t < TS; ++t) acc[t] = __fadd_rn(acc[t], part[t]);
    }
    __syncthreads();   // all maskL reads done before accL writes (aliased)

    #pragma unroll
    for (int t = 0; t < TS; ++t) accL[t * H + tid] = acc[t];
    // (each thread re-reads only its own accL slots — no barrier needed)

    // ---- Phase C: 25-step LIF scan, list-walk GEMM2/GEMM3 ----
    const float b1v = b1[tid];
    const float b2v = b2[tid];
    const float b3v = (tid < OUTP) ? b3[tid] : 0.0f;

    float c1 = 0, v1 = 0, s1 = 0;
    float c2 = 0, v2 = 0, s2 = 0;
    float c3 = 0, v3 = 0, s3 = 0, ct = 0;

    for (int t = 0; t < TS; ++t) {
        // ---- layer 1 LIF ----
        lif_step(accL[t * H + tid], b1v, c1, v1, s1);
        unsigned long long bal = __ballot(s1 != 0.0f);
        if (lane == 0) cw1[wave] = (uint32_t)__popcll(bal);
        __syncthreads();                                   // B1: cw1 visible
        int base = 0, cnt1 = 0;
        #pragma unroll
        for (int w = 0; w < 4; ++w) {
            if (w < wave) base += (int)cw1[w];
            cnt1 += (int)cw1[w];
        }
        if (s1 != 0.0f) list1[base + __popcll(bal & below)] = tid * H;
        __syncthreads();                                   // B2: list1 visible

        // ---- GEMM2: ascending-i chain over sorted list (K=256, 1 block) ----
        float a0 = walk_list(w2t, list1, cnt1, tid);

        // ---- layer 2 LIF ----
        lif_step(a0, b2v, c2, v2, s2);
        bal = __ballot(s2 != 0.0f);
        if (lane == 0) cw2[wave] = (uint32_t)__popcll(bal);
        __syncthreads();                                   // B3: cw2 visible
        int base2 = 0, cnt2 = 0;
        #pragma unroll
        for (int w = 0; w < 4; ++w) {
            if (w < wave) base2 += (int)cw2[w];
            cnt2 += (int)cw2[w];
        }
        if (s2 != 0.0f) list2[base2 + __popcll(bal & below)] = tid * OUTP;
        __syncthreads();                                   // B4: list2 visible

        // ---- GEMM3 + layer 3 LIF (threads 0..79) ----
        if (tid < OUTP) {
            float x = walk_list(w3t, list2, cnt2, tid);
            lif_step(x, b3v, c3, v3, s3);
            ct += s3;
        }
    }

    if (tid < OUTP) cnt3[tid] = ct;
    __syncthreads();

    // ---- decode: per-op rounding like np einsum (no FMA) ----
    if (tid < 8) {
        float raw = 0.0f;
        #pragma unroll
        for (int pp = 0; pp < POP; ++pp) {
            float po = __fdiv_rn(cnt3[tid * POP + pp], 25.0f);
            raw = __fadd_rn(raw, __fmul_rn(po, dw[tid * POP + pp]));
        }
        raw = __fadd_rn(raw, db[tid]);
        out[b * 8 + tid] = (float)tanh((double)raw);
    }
}

extern "C" void kernel_launch(void* const* d_in, const int* in_sizes, int n_in,
                              void* d_out, int out_size, void* d_ws, size_t ws_size,
                              hipStream_t stream) {
    const float* obs   = (const float*)d_in[0];
    const float* emean = (const float*)d_in[1];
    const float* estd  = (const float*)d_in[2];
    const float* w1    = (const float*)d_in[3];
    const float* b1    = (const float*)d_in[4];
    const float* w2    = (const float*)d_in[5];
    const float* b2    = (const float*)d_in[6];
    const float* w3    = (const float*)d_in[7];
    const float* b3    = (const float*)d_in[8];
    const float* dw    = (const float*)d_in[9];
    const float* db    = (const float*)d_in[10];
    float* out = (float*)d_out;

    char* ws = (char*)d_ws;
    float* w1t = (float*)(ws);                 // 655360 * 4 = 2,621,440 B
    float* w2t = (float*)(ws + 2621440);       //  65536 * 4 =   262,144 B
    float* w3t = (float*)(ws + 2883584);       //  20480 * 4 =    81,920 B

    k0_transpose<<<2896, 256, 0, stream>>>(w1, w2, w3, w1t, w2t, w3t);
    k1_fused<<<NB, 256, 0, stream>>>(obs, emean, estd, w1t, w2t, w3t,
                                     b1, b2, b3, dw, db, out);
}